// Round 1
// baseline (1859.655 us; speedup 1.0000x reference)
//
#include <hip/hip_runtime.h>
#include <math.h>

#define N_B 64
#define T_LEN 1024
#define IN_D 4
#define CH 5
#define SIG 780
// level offsets in the 780 vector: L1:0, L2:5, L3:30, L4:155

// ---------------- Kernel 1: time-aug + pointwise conv ----------------
__global__ __launch_bounds__(256) void conv_kernel(
    const float* __restrict__ batch,
    const float* __restrict__ conv_w,
    const float* __restrict__ conv_b,
    float* __restrict__ b_out) {
  int idx = blockIdx.x * blockDim.x + threadIdx.x;  // over N*T
  if (idx >= N_B * T_LEN) return;
  int t = idx & (T_LEN - 1);
  const float* a = batch + (size_t)idx * IN_D;
  float a0 = a[0], a1 = a[1], a2 = a[2], a3 = a[3];
  float tm = (float)(t + 1) / (float)T_LEN;
  float* o = b_out + (size_t)idx * CH;
#pragma unroll
  for (int j = 0; j < CH; ++j) {
    const float* w = conv_w + j * CH;
    float r = conv_b[j];
    r = fmaf(tm, w[4], r);
    r = fmaf(a3, w[3], r);
    r = fmaf(a2, w[2], r);
    r = fmaf(a1, w[1], r);
    r = fmaf(a0, w[0], r);
    o[j] = r;
  }
}

// ---------------- Kernel 2: streamed signature ----------------
// one block per batch element; 320 threads; state S[780] in LDS.
__global__ __launch_bounds__(320) void sig_kernel(
    const float* __restrict__ b_in,
    float* __restrict__ c_out) {
  int n = blockIdx.x;
  int tid = threadIdx.x;

  __shared__ float S[SIG];       // [0,5) L1, [5,30) L2, [30,155) L3, [155,780) L4
  __shared__ float bc[64 * CH];  // chunk of 64 path rows
  __shared__ float dsh[CH];
  __shared__ float pb[CH];

  for (int i = tid; i < SIG; i += 320) S[i] = 0.0f;
  if (tid < CH) pb[tid] = 0.0f;

  const float* bn = b_in + (size_t)n * T_LEN * CH;
  float* cn = c_out + (size_t)n * T_LEN * SIG;

  // precompute per-thread indices
  const int x0 = tid;                    // S4 entry 0 (always < 625 since tid<320)
  const int x1 = tid + 320;              // S4 entry 1, valid if tid < 305
  const bool has1 = (tid < 305);
  const int a0i = x0 / 125, b0i = (x0 / 25) % 5, c0i = (x0 / 5) % 5, d0i = x0 % 5;
  const int a1i = x1 / 125, b1i = (x1 / 25) % 5, c1i = (x1 / 5) % 5, d1i = x1 % 5;
  const int s2_0 = x0 / 25, s3_0 = x0 / 5;
  const int s2_1 = x1 / 25, s3_1 = x1 / 5;
  const bool hasL3 = (tid < 125);
  const int ya = tid / 25, yb = (tid / 5) % 5, yc = tid % 5;
  const bool hasL2 = (tid < 25);
  const int za = tid / 5, zb = tid % 5;
  const bool hasL1 = (tid < CH);

  for (int t = 0; t < T_LEN; ++t) {
    if ((t & 63) == 0) {
      __syncthreads();
      bc[tid] = bn[t * CH + tid];  // 320 consecutive floats = 64 rows
      __syncthreads();
    }
    // phase 0: increment d
    if (tid < CH) {
      float cur = bc[(t & 63) * CH + tid];
      dsh[tid] = cur - pb[tid];
      pb[tid] = cur;
    }
    __syncthreads();

    // phase A: compute new values from OLD state (no writes yet)
    float n4_0, n4_1 = 0.0f, n3 = 0.0f, n2 = 0.0f, n1 = 0.0f;
    {
      float s1 = S[a0i];
      float s2 = S[5 + s2_0];
      float s3 = S[30 + s3_0];
      float s4 = S[155 + x0];
      float tH = fmaf(0.25f, dsh[a0i], s1);
      tH = fmaf((1.0f / 3.0f) * dsh[b0i], tH, s2);
      tH = fmaf(0.5f * dsh[c0i], tH, s3);
      n4_0 = fmaf(dsh[d0i], tH, s4);
    }
    if (has1) {
      float s1 = S[a1i];
      float s2 = S[5 + s2_1];
      float s3 = S[30 + s3_1];
      float s4 = S[155 + x1];
      float tH = fmaf(0.25f, dsh[a1i], s1);
      tH = fmaf((1.0f / 3.0f) * dsh[b1i], tH, s2);
      tH = fmaf(0.5f * dsh[c1i], tH, s3);
      n4_1 = fmaf(dsh[d1i], tH, s4);
    }
    if (hasL3) {
      float s1 = S[ya];
      float s2 = S[5 + ya * 5 + yb];
      float s3 = S[30 + tid];
      float tH = fmaf((1.0f / 3.0f), dsh[ya], s1);
      tH = fmaf(0.5f * dsh[yb], tH, s2);
      n3 = fmaf(dsh[yc], tH, s3);
    }
    if (hasL2) {
      float s1 = S[za];
      float s2 = S[5 + tid];
      float tH = fmaf(0.5f, dsh[za], s1);
      n2 = fmaf(dsh[zb], tH, s2);
    }
    if (hasL1) {
      n1 = S[tid] + dsh[tid];
    }
    __syncthreads();

    // phase B: commit state + write c row (zeros at t==0 per reference)
    S[155 + x0] = n4_0;
    if (has1) S[155 + x1] = n4_1;
    if (hasL3) S[30 + tid] = n3;
    if (hasL2) S[5 + tid] = n2;
    if (hasL1) S[tid] = n1;

    float* crow = cn + (size_t)t * SIG;
    if (t == 0) {
      crow[155 + x0] = 0.0f;
      if (has1) crow[155 + x1] = 0.0f;
      if (hasL3) crow[30 + tid] = 0.0f;
      if (hasL2) crow[5 + tid] = 0.0f;
      if (hasL1) crow[tid] = 0.0f;
    } else {
      crow[155 + x0] = n4_0;
      if (has1) crow[155 + x1] = n4_1;
      if (hasL3) crow[30 + tid] = n3;
      if (hasL2) crow[5 + tid] = n2;
      if (hasL1) crow[tid] = n1;
    }
    __syncthreads();
  }
}

// ---------------- Kernel 3: fp32 GEMM (out = tanh(C * W^T + b)) ----------------
#define BM 256
#define BN 64
#define BK 16
__global__ __launch_bounds__(256) void gemm_tanh_kernel(
    const float* __restrict__ Cmat,  // M x 780
    const float* __restrict__ W,     // 780 x 780 (row-major; we need C*W^T)
    const float* __restrict__ bias,  // 780
    float* __restrict__ out) {       // M x 780
  __shared__ float As[BK][BM + 4];
  __shared__ float Ws[BK][BN + 4];

  int tid = threadIdx.x;
  int tx = tid & 7;    // N direction (8 threads * TN=8 = 64)
  int ty = tid >> 3;   // M direction (32 threads * TM=8 = 256)
  int m0 = blockIdx.x * BM;
  int n0 = blockIdx.y * BN;

  float acc[8][8];
#pragma unroll
  for (int i = 0; i < 8; ++i)
#pragma unroll
    for (int j = 0; j < 8; ++j) acc[i][j] = 0.0f;

  for (int kb = 0; kb < SIG; kb += BK) {
    __syncthreads();
    // A tile: 256 rows x 16 k (4 float4 per thread)
#pragma unroll
    for (int p = 0; p < 4; ++p) {
      int id = tid + p * 256;
      int row = id >> 2;
      int kg = (id & 3) * 4;
      int gk = kb + kg;
      float4 v = make_float4(0.f, 0.f, 0.f, 0.f);
      if (gk < SIG) v = *(const float4*)(Cmat + (size_t)(m0 + row) * SIG + gk);
      As[kg + 0][row] = v.x;
      As[kg + 1][row] = v.y;
      As[kg + 2][row] = v.z;
      As[kg + 3][row] = v.w;
    }
    // W tile: 64 rows x 16 k (1 float4 per thread)
    {
      int row = tid >> 2;
      int kg = (tid & 3) * 4;
      int gk = kb + kg;
      int wr = n0 + row;
      float4 v = make_float4(0.f, 0.f, 0.f, 0.f);
      if (gk < SIG && wr < SIG) v = *(const float4*)(W + (size_t)wr * SIG + gk);
      Ws[kg + 0][row] = v.x;
      Ws[kg + 1][row] = v.y;
      Ws[kg + 2][row] = v.z;
      Ws[kg + 3][row] = v.w;
    }
    __syncthreads();

#pragma unroll
    for (int k = 0; k < BK; ++k) {
      float af[8], wf[8];
      *(float4*)&af[0] = *(const float4*)&As[k][ty * 8];
      *(float4*)&af[4] = *(const float4*)&As[k][ty * 8 + 4];
      *(float4*)&wf[0] = *(const float4*)&Ws[k][tx * 8];
      *(float4*)&wf[4] = *(const float4*)&Ws[k][tx * 8 + 4];
#pragma unroll
      for (int i = 0; i < 8; ++i)
#pragma unroll
        for (int j = 0; j < 8; ++j)
          acc[i][j] = fmaf(af[i], wf[j], acc[i][j]);
    }
  }

  // epilogue: bias + tanh, float4 stores
#pragma unroll
  for (int i = 0; i < 8; ++i) {
    int m = m0 + ty * 8 + i;
    float* orow = out + (size_t)m * SIG;
#pragma unroll
    for (int jj = 0; jj < 8; jj += 4) {
      int col = n0 + tx * 8 + jj;
      if (col < SIG) {
        float4 r;
        r.x = tanhf(acc[i][jj + 0] + bias[col + 0]);
        r.y = tanhf(acc[i][jj + 1] + bias[col + 1]);
        r.z = tanhf(acc[i][jj + 2] + bias[col + 2]);
        r.w = tanhf(acc[i][jj + 3] + bias[col + 3]);
        *(float4*)(orow + col) = r;
      }
    }
  }
}

// ---------------- launch ----------------
extern "C" void kernel_launch(void* const* d_in, const int* in_sizes, int n_in,
                              void* d_out, int out_size, void* d_ws, size_t ws_size,
                              hipStream_t stream) {
  const float* batch = (const float*)d_in[0];   // (64,1024,4)
  const float* conv_w = (const float*)d_in[1];  // (5,5)
  const float* conv_b = (const float*)d_in[2];  // (5,)
  const float* lin_w = (const float*)d_in[3];   // (780,780)
  const float* lin_b = (const float*)d_in[4];   // (780,)
  float* out = (float*)d_out;                   // (64,1024,780)

  float* b_path = (float*)d_ws;                               // 64*1024*5 floats
  float* c_sig = (float*)d_ws + (size_t)N_B * T_LEN * CH;     // 64*1024*780 floats

  conv_kernel<<<dim3((N_B * T_LEN + 255) / 256), dim3(256), 0, stream>>>(
      batch, conv_w, conv_b, b_path);

  sig_kernel<<<dim3(N_B), dim3(320), 0, stream>>>(b_path, c_sig);

  gemm_tanh_kernel<<<dim3((N_B * T_LEN) / BM, (SIG + BN - 1) / BN), dim3(256), 0, stream>>>(
      c_sig, lin_w, lin_b, out);
}

// Round 2
// 846.347 us; speedup vs baseline: 2.1973x; 2.1973x over previous
//
#include <hip/hip_runtime.h>
#include <math.h>

#define N_B 64
#define T_LEN 1024
#define IN_D 4
#define CH 5
#define SIG 780
#define KP 800           // padded K for f16 planes
#define SEG_LEN 16
#define N_SEG 64
// level offsets: L1:0, L2:5, L3:30, L4:155
// level scales for f16 planes (power of 2, folded inversely into W planes)
#define SC_L1 1.0f
#define SC_L2 0.25f
#define SC_L3 0.0625f
#define SC_L4 0.015625f

typedef _Float16 f16x8 __attribute__((ext_vector_type(8)));
typedef float f32x4 __attribute__((ext_vector_type(4)));

typedef __attribute__((address_space(1))) const void* as1cp;
typedef __attribute__((address_space(3))) void* as3p;

// ---------------- Kernel 1: time-aug + pointwise conv ----------------
__global__ __launch_bounds__(256) void conv_kernel(
    const float* __restrict__ batch,
    const float* __restrict__ conv_w,
    const float* __restrict__ conv_b,
    float* __restrict__ b_out) {
  int idx = blockIdx.x * blockDim.x + threadIdx.x;
  if (idx >= N_B * T_LEN) return;
  int t = idx & (T_LEN - 1);
  const float* a = batch + (size_t)idx * IN_D;
  float a0 = a[0], a1 = a[1], a2 = a[2], a3 = a[3];
  float tm = (float)(t + 1) / (float)T_LEN;
  float* o = b_out + (size_t)idx * CH;
#pragma unroll
  for (int j = 0; j < CH; ++j) {
    const float* w = conv_w + j * CH;
    float r = conv_b[j];
    r = fmaf(tm, w[4], r);
    r = fmaf(a3, w[3], r);
    r = fmaf(a2, w[2], r);
    r = fmaf(a1, w[1], r);
    r = fmaf(a0, w[0], r);
    o[j] = r;
  }
}

// ---------------- Signature scan, phase A: per-segment signatures ----------------
// grid (seg=64, n=64), 320 threads. Writes P[n][seg][780] = signature of the
// segment's 16 increments starting from zero state.
__global__ __launch_bounds__(320) void seg_kernel(
    const float* __restrict__ b_in,
    float* __restrict__ P) {
  int s = blockIdx.x;
  int n = blockIdx.y;
  int tid = threadIdx.x;

  __shared__ float S[SIG];
  __shared__ float bc[(SEG_LEN + 1) * CH];  // 85 floats: rows s*16-1 .. s*16+15
  __shared__ float dsh[CH];

  for (int i = tid; i < SIG; i += 320) S[i] = 0.0f;
  const float* bn = b_in + (size_t)n * T_LEN * CH;
  if (tid < (SEG_LEN + 1) * CH) {
    int r = s * SEG_LEN - 1 + tid / CH;
    bc[tid] = (r < 0) ? 0.0f : bn[r * CH + tid % CH];
  }

  const int x0 = tid;
  const int x1 = tid + 320;
  const bool has1 = (tid < 305);
  const int a0i = x0 / 125, b0i = (x0 / 25) % 5, c0i = (x0 / 5) % 5, d0i = x0 % 5;
  const int a1i = x1 / 125, b1i = (x1 / 25) % 5, c1i = (x1 / 5) % 5, d1i = x1 % 5;
  const int s2_0 = x0 / 25, s3_0 = x0 / 5;
  const int s2_1 = x1 / 25, s3_1 = x1 / 5;
  const bool hasL3 = (tid < 125);
  const int ya = tid / 25, yb = (tid / 5) % 5, yc = tid % 5;
  const bool hasL2 = (tid < 25);
  const int za = tid / 5, zb = tid % 5;
  const bool hasL1 = (tid < CH);
  __syncthreads();

  for (int j = 0; j < SEG_LEN; ++j) {
    if (tid < CH) dsh[tid] = bc[(j + 1) * CH + tid] - bc[j * CH + tid];
    __syncthreads();
    float n4_0, n4_1 = 0.0f, n3 = 0.0f, n2 = 0.0f, n1 = 0.0f;
    {
      float tH = fmaf(0.25f, dsh[a0i], S[a0i]);
      tH = fmaf((1.0f / 3.0f) * dsh[b0i], tH, S[5 + s2_0]);
      tH = fmaf(0.5f * dsh[c0i], tH, S[30 + s3_0]);
      n4_0 = fmaf(dsh[d0i], tH, S[155 + x0]);
    }
    if (has1) {
      float tH = fmaf(0.25f, dsh[a1i], S[a1i]);
      tH = fmaf((1.0f / 3.0f) * dsh[b1i], tH, S[5 + s2_1]);
      tH = fmaf(0.5f * dsh[c1i], tH, S[30 + s3_1]);
      n4_1 = fmaf(dsh[d1i], tH, S[155 + x1]);
    }
    if (hasL3) {
      float tH = fmaf((1.0f / 3.0f), dsh[ya], S[ya]);
      tH = fmaf(0.5f * dsh[yb], tH, S[5 + ya * 5 + yb]);
      n3 = fmaf(dsh[yc], tH, S[30 + tid]);
    }
    if (hasL2) {
      float tH = fmaf(0.5f, dsh[za], S[za]);
      n2 = fmaf(dsh[zb], tH, S[5 + tid]);
    }
    if (hasL1) n1 = S[tid] + dsh[tid];
    __syncthreads();
    S[155 + x0] = n4_0;
    if (has1) S[155 + x1] = n4_1;
    if (hasL3) S[30 + tid] = n3;
    if (hasL2) S[5 + tid] = n2;
    if (hasL1) S[tid] = n1;
    __syncthreads();
  }

  float* Pr = P + ((size_t)n * N_SEG + s) * SIG;
  for (int i = tid; i < SIG; i += 320) Pr[i] = S[i];
}

// ---------------- Signature scan, phase B: sequential prefix over segments ---
// 64 blocks (one per n), 640 threads. In-place: P[n][s] becomes prefix sig.
__global__ __launch_bounds__(640) void prefix_kernel(float* __restrict__ P) {
  int n = blockIdx.x;
  int tid = threadIdx.x;
  __shared__ float A[SIG];   // running prefix
  __shared__ float B[SIG];   // current segment

  float* Pn = P + (size_t)n * N_SEG * SIG;
  for (int i = tid; i < SIG; i += 640) A[i] = Pn[i];

  // per-thread index decomposition (constant)
  const int e4 = tid;                 // L4 entry if tid<625
  const int q4a = e4 / 125, r125 = e4 % 125, r25 = e4 % 25, r5 = e4 % 5;
  const int e4_div5 = e4 / 5, e4_div25 = e4 / 25;
  const int e3 = tid;                 // L3 entry if tid<125
  const int e3a = e3 / 25, e3r25 = e3 % 25, e3r5 = e3 % 5, e3d5 = e3 / 5;
  const int e2 = tid - 125;           // L2 if 125<=tid<150
  const int e1 = tid - 150;           // L1 if 150<=tid<155

  for (int s = 1; s < N_SEG; ++s) {
    __syncthreads();
    const float* Ps = Pn + (size_t)s * SIG;
    for (int i = tid; i < SIG; i += 640) B[i] = Ps[i];
    __syncthreads();

    float v4 = 0.f, v3 = 0.f, v2 = 0.f, v1 = 0.f;
    if (tid < 625) {
      v4 = A[155 + e4] + B[155 + e4];
      v4 = fmaf(A[30 + e4_div5], B[r5], v4);
      v4 = fmaf(A[5 + e4_div25], B[5 + r25], v4);
      v4 = fmaf(A[q4a], B[30 + r125], v4);
    }
    if (tid < 125) {
      v3 = A[30 + e3] + B[30 + e3];
      v3 = fmaf(A[5 + e3d5], B[e3r5], v3);
      v3 = fmaf(A[e3a], B[5 + e3r25], v3);
    } else if (tid < 150) {
      v2 = A[5 + e2] + B[5 + e2];
      v2 = fmaf(A[e2 / 5], B[e2 % 5], v2);
    } else if (tid < 155) {
      v1 = A[e1] + B[e1];
    }
    __syncthreads();

    float* Po = Pn + (size_t)s * SIG;
    if (tid < 625) { A[155 + e4] = v4; Po[155 + e4] = v4; }
    if (tid < 125) { A[30 + e3] = v3; Po[30 + e3] = v3; }
    else if (tid < 150) { A[5 + e2] = v2; Po[5 + e2] = v2; }
    else if (tid < 155) { A[e1] = v1; Po[e1] = v1; }
  }
}

// ---------------- Signature scan, phase C: stream + emit f16 planes ----------
// grid (seg=64, n=64), 320 threads. Starts from P[n][s-1], streams 16 steps,
// writes scaled f16 hi/lo planes (row stride KP=800, cols [780,800) zeroed).
__global__ __launch_bounds__(320) void emit_kernel(
    const float* __restrict__ b_in,
    const float* __restrict__ P,
    _Float16* __restrict__ c1,
    _Float16* __restrict__ c2) {
  int s = blockIdx.x;
  int n = blockIdx.y;
  int tid = threadIdx.x;

  __shared__ float S[SIG];
  __shared__ float bc[(SEG_LEN + 1) * CH];
  __shared__ float dsh[CH];

  if (s == 0) {
    for (int i = tid; i < SIG; i += 320) S[i] = 0.0f;
  } else {
    const float* Pr = P + ((size_t)n * N_SEG + (s - 1)) * SIG;
    for (int i = tid; i < SIG; i += 320) S[i] = Pr[i];
  }
  const float* bn = b_in + (size_t)n * T_LEN * CH;
  if (tid < (SEG_LEN + 1) * CH) {
    int r = s * SEG_LEN - 1 + tid / CH;
    bc[tid] = (r < 0) ? 0.0f : bn[r * CH + tid % CH];
  }

  const int x0 = tid;
  const int x1 = tid + 320;
  const bool has1 = (tid < 305);
  const int a0i = x0 / 125, b0i = (x0 / 25) % 5, c0i = (x0 / 5) % 5, d0i = x0 % 5;
  const int a1i = x1 / 125, b1i = (x1 / 25) % 5, c1i = (x1 / 5) % 5, d1i = x1 % 5;
  const int s2_0 = x0 / 25, s3_0 = x0 / 5;
  const int s2_1 = x1 / 25, s3_1 = x1 / 5;
  const bool hasL3 = (tid < 125);
  const int ya = tid / 25, yb = (tid / 5) % 5, yc = tid % 5;
  const bool hasL2 = (tid < 25);
  const int za = tid / 5, zb = tid % 5;
  const bool hasL1 = (tid < CH);
  __syncthreads();

  for (int j = 0; j < SEG_LEN; ++j) {
    int t = s * SEG_LEN + j;
    if (tid < CH) dsh[tid] = bc[(j + 1) * CH + tid] - bc[j * CH + tid];
    __syncthreads();
    float n4_0, n4_1 = 0.0f, n3 = 0.0f, n2 = 0.0f, n1 = 0.0f;
    {
      float tH = fmaf(0.25f, dsh[a0i], S[a0i]);
      tH = fmaf((1.0f / 3.0f) * dsh[b0i], tH, S[5 + s2_0]);
      tH = fmaf(0.5f * dsh[c0i], tH, S[30 + s3_0]);
      n4_0 = fmaf(dsh[d0i], tH, S[155 + x0]);
    }
    if (has1) {
      float tH = fmaf(0.25f, dsh[a1i], S[a1i]);
      tH = fmaf((1.0f / 3.0f) * dsh[b1i], tH, S[5 + s2_1]);
      tH = fmaf(0.5f * dsh[c1i], tH, S[30 + s3_1]);
      n4_1 = fmaf(dsh[d1i], tH, S[155 + x1]);
    }
    if (hasL3) {
      float tH = fmaf((1.0f / 3.0f), dsh[ya], S[ya]);
      tH = fmaf(0.5f * dsh[yb], tH, S[5 + ya * 5 + yb]);
      n3 = fmaf(dsh[yc], tH, S[30 + tid]);
    }
    if (hasL2) {
      float tH = fmaf(0.5f, dsh[za], S[za]);
      n2 = fmaf(dsh[zb], tH, S[5 + tid]);
    }
    if (hasL1) n1 = S[tid] + dsh[tid];
    __syncthreads();
    S[155 + x0] = n4_0;
    if (has1) S[155 + x1] = n4_1;
    if (hasL3) S[30 + tid] = n3;
    if (hasL2) S[5 + tid] = n2;
    if (hasL1) S[tid] = n1;

    // emit row t (zeros at t==0), scaled, split into f16 hi/lo
    size_t row = ((size_t)n * T_LEN + t) * KP;
    _Float16* r1 = c1 + row;
    _Float16* r2 = c2 + row;
    float z = (t == 0) ? 0.0f : 1.0f;
    {
      float v = n4_0 * SC_L4 * z;
      _Float16 h = (_Float16)v;
      r1[155 + x0] = h; r2[155 + x0] = (_Float16)(v - (float)h);
    }
    if (has1) {
      float v = n4_1 * SC_L4 * z;
      _Float16 h = (_Float16)v;
      r1[155 + x1] = h; r2[155 + x1] = (_Float16)(v - (float)h);
    }
    if (hasL3) {
      float v = n3 * SC_L3 * z;
      _Float16 h = (_Float16)v;
      r1[30 + tid] = h; r2[30 + tid] = (_Float16)(v - (float)h);
    }
    if (hasL2) {
      float v = n2 * SC_L2 * z;
      _Float16 h = (_Float16)v;
      r1[5 + tid] = h; r2[5 + tid] = (_Float16)(v - (float)h);
    }
    if (hasL1) {
      float v = n1 * SC_L1 * z;
      _Float16 h = (_Float16)v;
      r1[tid] = h; r2[tid] = (_Float16)(v - (float)h);
    }
    if (tid < KP - SIG) {  // zero pad cols [780,800)
      r1[SIG + tid] = (_Float16)0.0f;
      r2[SIG + tid] = (_Float16)0.0f;
    }
    __syncthreads();
  }
}

// ---------------- W plane conversion (scaled, padded to 896x800) -------------
__global__ __launch_bounds__(256) void wconv_kernel(
    const float* __restrict__ W,
    _Float16* __restrict__ w1,
    _Float16* __restrict__ w2) {
  int idx = blockIdx.x * blockDim.x + threadIdx.x;
  if (idx >= 896 * KP) return;
  int nn = idx / KP, k = idx % KP;
  float v = 0.0f;
  if (nn < SIG && k < SIG) {
    float sc = (k < 5) ? 1.0f : (k < 30) ? 4.0f : (k < 155) ? 16.0f : 64.0f;
    v = W[(size_t)nn * SIG + k] * sc;
  }
  _Float16 h = (_Float16)v;
  w1[idx] = h;
  w2[idx] = (_Float16)(v - (float)h);
}

// ---------------- MFMA GEMM: out = tanh((c1+c2)*(w1+w2)^T + b) ---------------
// block tile 128(m) x 128(n), 4 waves in 2x2, wave tile 64x64 = 4x4 MFMA tiles
// of 16x16x32_f16; 4 products per tile (hi/lo x hi/lo) into one fp32 acc.
__global__ __launch_bounds__(256) void gemm_mfma(
    const _Float16* __restrict__ A1p, const _Float16* __restrict__ A2p,
    const _Float16* __restrict__ B1p, const _Float16* __restrict__ B2p,
    const float* __restrict__ bias, float* __restrict__ out) {
  __shared__ _Float16 Al[2][128 * 32];
  __shared__ _Float16 Bl[2][128 * 32];

  int tid = threadIdx.x;
  int lane = tid & 63, wid = tid >> 6;
  int wm = wid >> 1, wn = wid & 1;
  int m0 = blockIdx.y * 128;
  int n0 = blockIdx.x * 128;

  f32x4 acc[4][4];
#pragma unroll
  for (int i = 0; i < 4; ++i)
#pragma unroll
    for (int j = 0; j < 4; ++j) acc[i][j] = (f32x4){0.f, 0.f, 0.f, 0.f};

  // staging pattern: lane -> (row sr = lane>>2 within 16-row group, chunk sc)
  int sr = lane >> 2, scn = lane & 3;
  int swst = (sr ^ (sr >> 2)) & 3;
  int qg = scn ^ swst;  // which global 8-elem k-chunk this lane fetches
  // frag-read pattern
  int fr = lane & 15, fq = lane >> 4;
  int swf = (fr ^ (fr >> 2)) & 3;
  int fchunk = fq ^ swf;

  for (int kb = 0; kb < 25; ++kb) {
    int k0 = kb * 32;
    __syncthreads();
#pragma unroll
    for (int i = 0; i < 2; ++i) {
      int rloc = wid * 16 + i * 64 + sr;  // local row 0..127
      size_t gA = (size_t)(m0 + rloc) * KP + k0 + qg * 8;
      size_t gB = (size_t)(n0 + rloc) * KP + k0 + qg * 8;
      int lbase = (wid * 16 + i * 64) * 32;  // f16 elems; lane adds 8 elems
      __builtin_amdgcn_global_load_lds((as1cp)(A1p + gA), (as3p)(&Al[0][lbase]), 16, 0, 0);
      __builtin_amdgcn_global_load_lds((as1cp)(A2p + gA), (as3p)(&Al[1][lbase]), 16, 0, 0);
      __builtin_amdgcn_global_load_lds((as1cp)(B1p + gB), (as3p)(&Bl[0][lbase]), 16, 0, 0);
      __builtin_amdgcn_global_load_lds((as1cp)(B2p + gB), (as3p)(&Bl[1][lbase]), 16, 0, 0);
    }
    __syncthreads();

    f16x8 a1[4], a2[4], b1[4], b2[4];
#pragma unroll
    for (int tm = 0; tm < 4; ++tm) {
      int off = (wm * 64 + tm * 16 + fr) * 32 + fchunk * 8;
      a1[tm] = *(const f16x8*)&Al[0][off];
      a2[tm] = *(const f16x8*)&Al[1][off];
    }
#pragma unroll
    for (int tn = 0; tn < 4; ++tn) {
      int off = (wn * 64 + tn * 16 + fr) * 32 + fchunk * 8;
      b1[tn] = *(const f16x8*)&Bl[0][off];
      b2[tn] = *(const f16x8*)&Bl[1][off];
    }
#pragma unroll
    for (int tm = 0; tm < 4; ++tm)
#pragma unroll
      for (int tn = 0; tn < 4; ++tn) {
        acc[tm][tn] = __builtin_amdgcn_mfma_f32_16x16x32_f16(a1[tm], b1[tn], acc[tm][tn], 0, 0, 0);
        acc[tm][tn] = __builtin_amdgcn_mfma_f32_16x16x32_f16(a1[tm], b2[tn], acc[tm][tn], 0, 0, 0);
        acc[tm][tn] = __builtin_amdgcn_mfma_f32_16x16x32_f16(a2[tm], b1[tn], acc[tm][tn], 0, 0, 0);
        acc[tm][tn] = __builtin_amdgcn_mfma_f32_16x16x32_f16(a2[tm], b2[tn], acc[tm][tn], 0, 0, 0);
      }
  }

  // epilogue: C/D layout col=lane&15 (n), row=(lane>>4)*4+reg (m)
  float bv[4];
#pragma unroll
  for (int tn = 0; tn < 4; ++tn) {
    int nn = n0 + wn * 64 + tn * 16 + fr;
    bv[tn] = (nn < SIG) ? bias[nn] : 0.0f;
  }
#pragma unroll
  for (int tm = 0; tm < 4; ++tm) {
    int mg = m0 + wm * 64 + tm * 16 + fq * 4;
#pragma unroll
    for (int tn = 0; tn < 4; ++tn) {
      int nn = n0 + wn * 64 + tn * 16 + fr;
      if (nn < SIG) {
        float* op = out + (size_t)mg * SIG + nn;
#pragma unroll
        for (int r = 0; r < 4; ++r)
          op[(size_t)r * SIG] = tanhf(acc[tm][tn][r] + bv[tn]);
      }
    }
  }
}

// ================= FALLBACK PATH (round-1, fp32) =============================
__global__ __launch_bounds__(320) void sig_kernel_fb(
    const float* __restrict__ b_in, float* __restrict__ c_out) {
  int n = blockIdx.x;
  int tid = threadIdx.x;
  __shared__ float S[SIG];
  __shared__ float bc[64 * CH];
  __shared__ float dsh[CH];
  __shared__ float pb[CH];
  for (int i = tid; i < SIG; i += 320) S[i] = 0.0f;
  if (tid < CH) pb[tid] = 0.0f;
  const float* bn = b_in + (size_t)n * T_LEN * CH;
  float* cn = c_out + (size_t)n * T_LEN * SIG;
  const int x0 = tid, x1 = tid + 320;
  const bool has1 = (tid < 305);
  const int a0i = x0 / 125, b0i = (x0 / 25) % 5, c0i = (x0 / 5) % 5, d0i = x0 % 5;
  const int a1i = x1 / 125, b1i = (x1 / 25) % 5, c1i = (x1 / 5) % 5, d1i = x1 % 5;
  const int s2_0 = x0 / 25, s3_0 = x0 / 5, s2_1 = x1 / 25, s3_1 = x1 / 5;
  const bool hasL3 = (tid < 125);
  const int ya = tid / 25, yb = (tid / 5) % 5, yc = tid % 5;
  const bool hasL2 = (tid < 25);
  const int za = tid / 5, zb = tid % 5;
  const bool hasL1 = (tid < CH);
  for (int t = 0; t < T_LEN; ++t) {
    if ((t & 63) == 0) {
      __syncthreads();
      bc[tid] = bn[t * CH + tid];
      __syncthreads();
    }
    if (tid < CH) {
      float cur = bc[(t & 63) * CH + tid];
      dsh[tid] = cur - pb[tid];
      pb[tid] = cur;
    }
    __syncthreads();
    float n4_0, n4_1 = 0.0f, n3 = 0.0f, n2 = 0.0f, n1 = 0.0f;
    {
      float tH = fmaf(0.25f, dsh[a0i], S[a0i]);
      tH = fmaf((1.0f / 3.0f) * dsh[b0i], tH, S[5 + s2_0]);
      tH = fmaf(0.5f * dsh[c0i], tH, S[30 + s3_0]);
      n4_0 = fmaf(dsh[d0i], tH, S[155 + x0]);
    }
    if (has1) {
      float tH = fmaf(0.25f, dsh[a1i], S[a1i]);
      tH = fmaf((1.0f / 3.0f) * dsh[b1i], tH, S[5 + s2_1]);
      tH = fmaf(0.5f * dsh[c1i], tH, S[30 + s3_1]);
      n4_1 = fmaf(dsh[d1i], tH, S[155 + x1]);
    }
    if (hasL3) {
      float tH = fmaf((1.0f / 3.0f), dsh[ya], S[ya]);
      tH = fmaf(0.5f * dsh[yb], tH, S[5 + ya * 5 + yb]);
      n3 = fmaf(dsh[yc], tH, S[30 + tid]);
    }
    if (hasL2) {
      float tH = fmaf(0.5f, dsh[za], S[za]);
      n2 = fmaf(dsh[zb], tH, S[5 + tid]);
    }
    if (hasL1) n1 = S[tid] + dsh[tid];
    __syncthreads();
    S[155 + x0] = n4_0;
    if (has1) S[155 + x1] = n4_1;
    if (hasL3) S[30 + tid] = n3;
    if (hasL2) S[5 + tid] = n2;
    if (hasL1) S[tid] = n1;
    float* crow = cn + (size_t)t * SIG;
    float z = (t == 0) ? 0.0f : 1.0f;
    crow[155 + x0] = n4_0 * z;
    if (has1) crow[155 + x1] = n4_1 * z;
    if (hasL3) crow[30 + tid] = n3 * z;
    if (hasL2) crow[5 + tid] = n2 * z;
    if (hasL1) crow[tid] = n1 * z;
    __syncthreads();
  }
}

#define BM 256
#define BN 64
#define BK 16
__global__ __launch_bounds__(256) void gemm_tanh_fb(
    const float* __restrict__ Cmat, const float* __restrict__ W,
    const float* __restrict__ bias, float* __restrict__ out) {
  __shared__ float As[BK][BM + 4];
  __shared__ float Ws[BK][BN + 4];
  int tid = threadIdx.x;
  int tx = tid & 7, ty = tid >> 3;
  int m0 = blockIdx.x * BM, n0 = blockIdx.y * BN;
  float acc[8][8];
#pragma unroll
  for (int i = 0; i < 8; ++i)
#pragma unroll
    for (int j = 0; j < 8; ++j) acc[i][j] = 0.0f;
  for (int kb = 0; kb < SIG; kb += BK) {
    __syncthreads();
#pragma unroll
    for (int p = 0; p < 4; ++p) {
      int id = tid + p * 256;
      int row = id >> 2, kg = (id & 3) * 4, gk = kb + kg;
      float4 v = make_float4(0.f, 0.f, 0.f, 0.f);
      if (gk < SIG) v = *(const float4*)(Cmat + (size_t)(m0 + row) * SIG + gk);
      As[kg + 0][row] = v.x; As[kg + 1][row] = v.y;
      As[kg + 2][row] = v.z; As[kg + 3][row] = v.w;
    }
    {
      int row = tid >> 2, kg = (tid & 3) * 4, gk = kb + kg, wr = n0 + row;
      float4 v = make_float4(0.f, 0.f, 0.f, 0.f);
      if (gk < SIG && wr < SIG) v = *(const float4*)(W + (size_t)wr * SIG + gk);
      Ws[kg + 0][row] = v.x; Ws[kg + 1][row] = v.y;
      Ws[kg + 2][row] = v.z; Ws[kg + 3][row] = v.w;
    }
    __syncthreads();
#pragma unroll
    for (int k = 0; k < BK; ++k) {
      float af[8], wf[8];
      *(float4*)&af[0] = *(const float4*)&As[k][ty * 8];
      *(float4*)&af[4] = *(const float4*)&As[k][ty * 8 + 4];
      *(float4*)&wf[0] = *(const float4*)&Ws[k][tx * 8];
      *(float4*)&wf[4] = *(const float4*)&Ws[k][tx * 8 + 4];
#pragma unroll
      for (int i = 0; i < 8; ++i)
#pragma unroll
        for (int j = 0; j < 8; ++j) acc[i][j] = fmaf(af[i], wf[j], acc[i][j]);
    }
  }
#pragma unroll
  for (int i = 0; i < 8; ++i) {
    int m = m0 + ty * 8 + i;
    float* orow = out + (size_t)m * SIG;
#pragma unroll
    for (int jj = 0; jj < 8; jj += 4) {
      int col = n0 + tx * 8 + jj;
      if (col < SIG) {
        float4 r;
        r.x = tanhf(acc[i][jj + 0] + bias[col + 0]);
        r.y = tanhf(acc[i][jj + 1] + bias[col + 1]);
        r.z = tanhf(acc[i][jj + 2] + bias[col + 2]);
        r.w = tanhf(acc[i][jj + 3] + bias[col + 3]);
        *(float4*)(orow + col) = r;
      }
    }
  }
}

// ---------------- launch ----------------
extern "C" void kernel_launch(void* const* d_in, const int* in_sizes, int n_in,
                              void* d_out, int out_size, void* d_ws, size_t ws_size,
                              hipStream_t stream) {
  const float* batch = (const float*)d_in[0];
  const float* conv_w = (const float*)d_in[1];
  const float* conv_b = (const float*)d_in[2];
  const float* lin_w = (const float*)d_in[3];
  const float* lin_b = (const float*)d_in[4];
  float* out = (float*)d_out;

  const size_t plane_elems = (size_t)N_B * T_LEN * KP;        // 52,428,800
  const size_t wplane_elems = (size_t)896 * KP;               // 716,800
  const size_t P_elems = (size_t)N_B * N_SEG * SIG;           // 3,194,880
  const size_t bp_elems = (size_t)N_B * T_LEN * CH;           // 327,680
  const size_t need_big = 2 * plane_elems * sizeof(_Float16) +
                          2 * wplane_elems * sizeof(_Float16) +
                          (P_elems + bp_elems) * sizeof(float);  // ~226.7 MB

  if (ws_size >= need_big) {
    _Float16* c1 = (_Float16*)d_ws;
    _Float16* c2 = c1 + plane_elems;
    _Float16* w1 = c2 + plane_elems;
    _Float16* w2 = w1 + wplane_elems;
    float* P = (float*)(w2 + wplane_elems);
    float* b_path = P + P_elems;

    conv_kernel<<<dim3((N_B * T_LEN + 255) / 256), dim3(256), 0, stream>>>(
        batch, conv_w, conv_b, b_path);
    wconv_kernel<<<dim3((896 * KP + 255) / 256), dim3(256), 0, stream>>>(
        lin_w, w1, w2);
    seg_kernel<<<dim3(N_SEG, N_B), dim3(320), 0, stream>>>(b_path, P);
    prefix_kernel<<<dim3(N_B), dim3(640), 0, stream>>>(P);
    emit_kernel<<<dim3(N_SEG, N_B), dim3(320), 0, stream>>>(b_path, P, c1, c2);
    gemm_mfma<<<dim3(7, 512), dim3(256), 0, stream>>>(c1, c2, w1, w2, lin_b, out);
  } else {
    float* b_path = (float*)d_ws;
    float* c_sig = (float*)d_ws + bp_elems;
    conv_kernel<<<dim3((N_B * T_LEN + 255) / 256), dim3(256), 0, stream>>>(
        batch, conv_w, conv_b, b_path);
    sig_kernel_fb<<<dim3(N_B), dim3(320), 0, stream>>>(b_path, c_sig);
    gemm_tanh_fb<<<dim3((N_B * T_LEN) / BM, (SIG + BN - 1) / BN), dim3(256), 0, stream>>>(
        c_sig, lin_w, lin_b, out);
  }
}

// Round 3
// 724.481 us; speedup vs baseline: 2.5669x; 1.1682x over previous
//
#include <hip/hip_runtime.h>
#include <math.h>

#define N_B 64
#define T_LEN 1024
#define IN_D 4
#define CH 5
#define SIG 780
#define KP 800           // padded K for f16 planes
#define SEG_LEN 16
#define N_SEG 64
// level offsets: L1:0, L2:5, L3:30, L4:155
// level scales for f16 planes (power of 2, folded inversely into W planes)
#define SC_L1 1.0f
#define SC_L2 0.25f
#define SC_L3 0.0625f
#define SC_L4 0.015625f

typedef _Float16 f16x8 __attribute__((ext_vector_type(8)));
typedef float f32x4 __attribute__((ext_vector_type(4)));

typedef __attribute__((address_space(1))) const void* as1cp;
typedef __attribute__((address_space(3))) void* as3p;

__device__ __forceinline__ float fast_tanh(float x) {
  float ax = fabsf(x);
  float e = __expf(-2.0f * ax);
  float r = (1.0f - e) * __builtin_amdgcn_rcpf(1.0f + e);
  return copysignf(r, x);
}

// ---------------- Kernel 1 (fallback only): time-aug + pointwise conv -------
__global__ __launch_bounds__(256) void conv_kernel(
    const float* __restrict__ batch,
    const float* __restrict__ conv_w,
    const float* __restrict__ conv_b,
    float* __restrict__ b_out) {
  int idx = blockIdx.x * blockDim.x + threadIdx.x;
  if (idx >= N_B * T_LEN) return;
  int t = idx & (T_LEN - 1);
  const float* a = batch + (size_t)idx * IN_D;
  float a0 = a[0], a1 = a[1], a2 = a[2], a3 = a[3];
  float tm = (float)(t + 1) / (float)T_LEN;
  float* o = b_out + (size_t)idx * CH;
#pragma unroll
  for (int j = 0; j < CH; ++j) {
    const float* w = conv_w + j * CH;
    float r = conv_b[j];
    r = fmaf(tm, w[4], r);
    r = fmaf(a3, w[3], r);
    r = fmaf(a2, w[2], r);
    r = fmaf(a1, w[1], r);
    r = fmaf(a0, w[0], r);
    o[j] = r;
  }
}

// ---------------- Signature phase A: per-segment signatures (conv fused) ----
__global__ __launch_bounds__(320) void seg_kernel(
    const float* __restrict__ batch,
    const float* __restrict__ conv_w,
    const float* __restrict__ conv_b,
    float* __restrict__ P) {
  int s = blockIdx.x;
  int n = blockIdx.y;
  int tid = threadIdx.x;

  __shared__ float S[SIG];
  __shared__ float bc[(SEG_LEN + 1) * CH];
  __shared__ float dsh[SEG_LEN][CH];

  for (int i = tid; i < SIG; i += 320) S[i] = 0.0f;
  if (tid < (SEG_LEN + 1) * CH) {
    int r = s * SEG_LEN - 1 + tid / CH, ch = tid % CH;
    float v = 0.0f;
    if (r >= 0) {
      const float* a = batch + ((size_t)n * T_LEN + r) * IN_D;
      const float* w = conv_w + ch * CH;
      v = conv_b[ch];
      v = fmaf(a[0], w[0], v);
      v = fmaf(a[1], w[1], v);
      v = fmaf(a[2], w[2], v);
      v = fmaf(a[3], w[3], v);
      v = fmaf((float)(r + 1) * (1.0f / T_LEN), w[4], v);
    }
    bc[tid] = v;
  }
  __syncthreads();
  if (tid < SEG_LEN * CH) {
    int j = tid / CH, ch = tid % CH;
    dsh[j][ch] = bc[(j + 1) * CH + ch] - bc[j * CH + ch];
  }

  const int x0 = tid;
  const int x1 = tid + 320;
  const bool has1 = (tid < 305);
  const int a0i = x0 / 125, b0i = (x0 / 25) % 5, c0i = (x0 / 5) % 5, d0i = x0 % 5;
  const int a1i = x1 / 125, b1i = (x1 / 25) % 5, c1i = (x1 / 5) % 5, d1i = x1 % 5;
  const int s2_0 = x0 / 25, s3_0 = x0 / 5;
  const int s2_1 = x1 / 25, s3_1 = x1 / 5;
  const bool hasL3 = (tid < 125);
  const int ya = tid / 25, yb = (tid / 5) % 5, yc = tid % 5;
  const bool hasL2 = (tid < 25);
  const int za = tid / 5, zb = tid % 5;
  const bool hasL1 = (tid < CH);
  __syncthreads();

  for (int j = 0; j < SEG_LEN; ++j) {
    float n4_0, n4_1 = 0.0f, n3 = 0.0f, n2 = 0.0f, n1 = 0.0f;
    {
      float tH = fmaf(0.25f, dsh[j][a0i], S[a0i]);
      tH = fmaf((1.0f / 3.0f) * dsh[j][b0i], tH, S[5 + s2_0]);
      tH = fmaf(0.5f * dsh[j][c0i], tH, S[30 + s3_0]);
      n4_0 = fmaf(dsh[j][d0i], tH, S[155 + x0]);
    }
    if (has1) {
      float tH = fmaf(0.25f, dsh[j][a1i], S[a1i]);
      tH = fmaf((1.0f / 3.0f) * dsh[j][b1i], tH, S[5 + s2_1]);
      tH = fmaf(0.5f * dsh[j][c1i], tH, S[30 + s3_1]);
      n4_1 = fmaf(dsh[j][d1i], tH, S[155 + x1]);
    }
    if (hasL3) {
      float tH = fmaf((1.0f / 3.0f), dsh[j][ya], S[ya]);
      tH = fmaf(0.5f * dsh[j][yb], tH, S[5 + ya * 5 + yb]);
      n3 = fmaf(dsh[j][yc], tH, S[30 + tid]);
    }
    if (hasL2) {
      float tH = fmaf(0.5f, dsh[j][za], S[za]);
      n2 = fmaf(dsh[j][zb], tH, S[5 + tid]);
    }
    if (hasL1) n1 = S[tid] + dsh[j][tid];
    __syncthreads();
    S[155 + x0] = n4_0;
    if (has1) S[155 + x1] = n4_1;
    if (hasL3) S[30 + tid] = n3;
    if (hasL2) S[5 + tid] = n2;
    if (hasL1) S[tid] = n1;
    __syncthreads();
  }

  float* Pr = P + ((size_t)n * N_SEG + s) * SIG;
  for (int i = tid; i < SIG; i += 320) Pr[i] = S[i];
}

// ---------------- Signature phase B: sequential prefix (reg-prefetched) -----
__global__ __launch_bounds__(640) void prefix_kernel(float* __restrict__ P) {
  int n = blockIdx.x;
  int tid = threadIdx.x;
  __shared__ float A[SIG];
  __shared__ float Bs[SIG];

  float* Pn = P + (size_t)n * N_SEG * SIG;
  for (int i = tid; i < SIG; i += 640) A[i] = Pn[i];
  int i0 = tid, i1 = tid + 640;
  float r0 = 0.f, r1 = 0.f;
  if (i0 < SIG) r0 = Pn[SIG + i0];
  if (i1 < SIG) r1 = Pn[SIG + i1];

  const int e4 = tid;
  const int q4a = e4 / 125, r125 = e4 % 125, r25 = e4 % 25, r5 = e4 % 5;
  const int e4d5 = e4 / 5, e4d25 = e4 / 25;
  const int e3 = tid;
  const int e3a = e3 / 25, e3r25 = e3 % 25, e3r5 = e3 % 5, e3d5 = e3 / 5;
  const int e2 = tid - 125;
  const int e1 = tid - 150;

  for (int s = 1; s < N_SEG; ++s) {
    if (i0 < SIG) Bs[i0] = r0;
    if (i1 < SIG) Bs[i1] = r1;
    __syncthreads();
    if (s + 1 < N_SEG) {
      const float* Pnx = Pn + (size_t)(s + 1) * SIG;
      if (i0 < SIG) r0 = Pnx[i0];
      if (i1 < SIG) r1 = Pnx[i1];
    }
    float v4 = 0.f, v3 = 0.f, v2 = 0.f, v1 = 0.f;
    if (tid < 625) {
      v4 = A[155 + e4] + Bs[155 + e4];
      v4 = fmaf(A[30 + e4d5], Bs[r5], v4);
      v4 = fmaf(A[5 + e4d25], Bs[5 + r25], v4);
      v4 = fmaf(A[q4a], Bs[30 + r125], v4);
    }
    if (tid < 125) {
      v3 = A[30 + e3] + Bs[30 + e3];
      v3 = fmaf(A[5 + e3d5], Bs[e3r5], v3);
      v3 = fmaf(A[e3a], Bs[5 + e3r25], v3);
    } else if (tid < 150) {
      v2 = A[5 + e2] + Bs[5 + e2];
      v2 = fmaf(A[e2 / 5], Bs[e2 % 5], v2);
    } else if (tid < 155) {
      v1 = A[e1] + Bs[e1];
    }
    __syncthreads();
    float* Po = Pn + (size_t)s * SIG;
    if (tid < 625) { A[155 + e4] = v4; Po[155 + e4] = v4; }
    if (tid < 125) { A[30 + e3] = v3; Po[30 + e3] = v3; }
    else if (tid < 150) { A[5 + e2] = v2; Po[5 + e2] = v2; }
    else if (tid < 155) { A[e1] = v1; Po[e1] = v1; }
  }
}

// ---------------- Signature phase C: stream + emit f16 planes (coalesced) ---
__global__ __launch_bounds__(320) void emit_kernel(
    const float* __restrict__ batch,
    const float* __restrict__ conv_w,
    const float* __restrict__ conv_b,
    const float* __restrict__ P,
    _Float16* __restrict__ c1,
    _Float16* __restrict__ c2) {
  int s = blockIdx.x;
  int n = blockIdx.y;
  int tid = threadIdx.x;

  __shared__ float S[SIG];
  __shared__ float bc[(SEG_LEN + 1) * CH];
  __shared__ float dsh[SEG_LEN][CH];
  __shared__ __align__(16) _Float16 row1[KP];
  __shared__ __align__(16) _Float16 row2[KP];

  if (s == 0) {
    for (int i = tid; i < SIG; i += 320) S[i] = 0.0f;
  } else {
    const float* Pr = P + ((size_t)n * N_SEG + (s - 1)) * SIG;
    for (int i = tid; i < SIG; i += 320) S[i] = Pr[i];
  }
  if (tid < (SEG_LEN + 1) * CH) {
    int r = s * SEG_LEN - 1 + tid / CH, ch = tid % CH;
    float v = 0.0f;
    if (r >= 0) {
      const float* a = batch + ((size_t)n * T_LEN + r) * IN_D;
      const float* w = conv_w + ch * CH;
      v = conv_b[ch];
      v = fmaf(a[0], w[0], v);
      v = fmaf(a[1], w[1], v);
      v = fmaf(a[2], w[2], v);
      v = fmaf(a[3], w[3], v);
      v = fmaf((float)(r + 1) * (1.0f / T_LEN), w[4], v);
    }
    bc[tid] = v;
  }
  if (tid < KP - SIG) {  // zero the pad tail once
    row1[SIG + tid] = (_Float16)0.0f;
    row2[SIG + tid] = (_Float16)0.0f;
  }
  __syncthreads();
  if (tid < SEG_LEN * CH) {
    int j = tid / CH, ch = tid % CH;
    dsh[j][ch] = bc[(j + 1) * CH + ch] - bc[j * CH + ch];
  }

  const int x0 = tid;
  const int x1 = tid + 320;
  const bool has1 = (tid < 305);
  const int a0i = x0 / 125, b0i = (x0 / 25) % 5, c0i = (x0 / 5) % 5, d0i = x0 % 5;
  const int a1i = x1 / 125, b1i = (x1 / 25) % 5, c1i = (x1 / 5) % 5, d1i = x1 % 5;
  const int s2_0 = x0 / 25, s3_0 = x0 / 5;
  const int s2_1 = x1 / 25, s3_1 = x1 / 5;
  const bool hasL3 = (tid < 125);
  const int ya = tid / 25, yb = (tid / 5) % 5, yc = tid % 5;
  const bool hasL2 = (tid < 25);
  const int za = tid / 5, zb = tid % 5;
  const bool hasL1 = (tid < CH);
  __syncthreads();

  for (int j = 0; j < SEG_LEN; ++j) {
    int t = s * SEG_LEN + j;
    float n4_0, n4_1 = 0.0f, n3 = 0.0f, n2 = 0.0f, n1 = 0.0f;
    {
      float tH = fmaf(0.25f, dsh[j][a0i], S[a0i]);
      tH = fmaf((1.0f / 3.0f) * dsh[j][b0i], tH, S[5 + s2_0]);
      tH = fmaf(0.5f * dsh[j][c0i], tH, S[30 + s3_0]);
      n4_0 = fmaf(dsh[j][d0i], tH, S[155 + x0]);
    }
    if (has1) {
      float tH = fmaf(0.25f, dsh[j][a1i], S[a1i]);
      tH = fmaf((1.0f / 3.0f) * dsh[j][b1i], tH, S[5 + s2_1]);
      tH = fmaf(0.5f * dsh[j][c1i], tH, S[30 + s3_1]);
      n4_1 = fmaf(dsh[j][d1i], tH, S[155 + x1]);
    }
    if (hasL3) {
      float tH = fmaf((1.0f / 3.0f), dsh[j][ya], S[ya]);
      tH = fmaf(0.5f * dsh[j][yb], tH, S[5 + ya * 5 + yb]);
      n3 = fmaf(dsh[j][yc], tH, S[30 + tid]);
    }
    if (hasL2) {
      float tH = fmaf(0.5f, dsh[j][za], S[za]);
      n2 = fmaf(dsh[j][zb], tH, S[5 + tid]);
    }
    if (hasL1) n1 = S[tid] + dsh[j][tid];
    __syncthreads();

    // commit state + build scaled f16 row in LDS
    S[155 + x0] = n4_0;
    if (has1) S[155 + x1] = n4_1;
    if (hasL3) S[30 + tid] = n3;
    if (hasL2) S[5 + tid] = n2;
    if (hasL1) S[tid] = n1;

    float z = (t == 0) ? 0.0f : 1.0f;
    {
      float v = n4_0 * SC_L4 * z;
      _Float16 h = (_Float16)v;
      row1[155 + x0] = h; row2[155 + x0] = (_Float16)(v - (float)h);
    }
    if (has1) {
      float v = n4_1 * SC_L4 * z;
      _Float16 h = (_Float16)v;
      row1[155 + x1] = h; row2[155 + x1] = (_Float16)(v - (float)h);
    }
    if (hasL3) {
      float v = n3 * SC_L3 * z;
      _Float16 h = (_Float16)v;
      row1[30 + tid] = h; row2[30 + tid] = (_Float16)(v - (float)h);
    }
    if (hasL2) {
      float v = n2 * SC_L2 * z;
      _Float16 h = (_Float16)v;
      row1[5 + tid] = h; row2[5 + tid] = (_Float16)(v - (float)h);
    }
    if (hasL1) {
      float v = n1 * SC_L1 * z;
      _Float16 h = (_Float16)v;
      row1[tid] = h; row2[tid] = (_Float16)(v - (float)h);
    }
    __syncthreads();

    // coalesced 16B-chunk store of the row (100 chunks per plane)
    size_t base = ((size_t)n * T_LEN + t) * KP;
    if (tid < 100) {
      *(float4*)(c1 + base + tid * 8) = *(const float4*)&row1[tid * 8];
    } else if (tid < 200) {
      int c = tid - 100;
      *(float4*)(c2 + base + c * 8) = *(const float4*)&row2[c * 8];
    }
  }
}

// ---------------- W plane conversion (scaled, padded to 896x800) -------------
__global__ __launch_bounds__(256) void wconv_kernel(
    const float* __restrict__ W,
    _Float16* __restrict__ w1,
    _Float16* __restrict__ w2) {
  int idx = blockIdx.x * blockDim.x + threadIdx.x;
  if (idx >= 896 * KP) return;
  int nn = idx / KP, k = idx % KP;
  float v = 0.0f;
  if (nn < SIG && k < SIG) {
    float sc = (k < 5) ? 1.0f : (k < 30) ? 4.0f : (k < 155) ? 16.0f : 64.0f;
    v = W[(size_t)nn * SIG + k] * sc;
  }
  _Float16 h = (_Float16)v;
  w1[idx] = h;
  w2[idx] = (_Float16)(v - (float)h);
}

// ---------------- MFMA GEMM: out = tanh((c1+c2)*(w1+w2)^T + b) ---------------
// 128x128 block tile, 4 waves 2x2, wave tile 64x64 = 4x4 of 16x16x32_f16.
// 3 products (hi*hi, hi*lo, lo*hi). Double-buffered LDS; per-iter order:
// barrier (drains prev loads) -> ds_read frags -> issue async loads k+1 -> MFMA.
__global__ __launch_bounds__(256) void gemm_mfma(
    const _Float16* __restrict__ A1p, const _Float16* __restrict__ A2p,
    const _Float16* __restrict__ B1p, const _Float16* __restrict__ B2p,
    const float* __restrict__ bias, float* __restrict__ out) {
  __shared__ _Float16 Al[2][2][128 * 32];  // [buf][plane]
  __shared__ _Float16 Bl[2][2][128 * 32];

  int tid = threadIdx.x;
  int lane = tid & 63, wid = tid >> 6;
  int wm = wid >> 1, wn = wid & 1;
  int m0 = blockIdx.y * 128;
  int n0 = blockIdx.x * 128;

  f32x4 acc[4][4];
#pragma unroll
  for (int i = 0; i < 4; ++i)
#pragma unroll
    for (int j = 0; j < 4; ++j) acc[i][j] = (f32x4){0.f, 0.f, 0.f, 0.f};

  int sr = lane >> 2, scn = lane & 3;
  int swst = (sr ^ (sr >> 2)) & 3;
  int qg = scn ^ swst;
  int fr = lane & 15, fq = lane >> 4;
  int swf = (fr ^ (fr >> 2)) & 3;
  int fchunk = fq ^ swf;

  auto stage = [&](int kb, int buf) {
    int k0 = kb * 32;
#pragma unroll
    for (int i = 0; i < 2; ++i) {
      int rloc = wid * 16 + i * 64 + sr;
      size_t gA = (size_t)(m0 + rloc) * KP + k0 + qg * 8;
      size_t gB = (size_t)(n0 + rloc) * KP + k0 + qg * 8;
      int lb = (wid * 16 + i * 64) * 32;
      __builtin_amdgcn_global_load_lds((as1cp)(A1p + gA), (as3p)(&Al[buf][0][lb]), 16, 0, 0);
      __builtin_amdgcn_global_load_lds((as1cp)(A2p + gA), (as3p)(&Al[buf][1][lb]), 16, 0, 0);
      __builtin_amdgcn_global_load_lds((as1cp)(B1p + gB), (as3p)(&Bl[buf][0][lb]), 16, 0, 0);
      __builtin_amdgcn_global_load_lds((as1cp)(B2p + gB), (as3p)(&Bl[buf][1][lb]), 16, 0, 0);
    }
  };

  stage(0, 0);
  for (int kb = 0; kb < 25; ++kb) {
    int cur = kb & 1;
    __syncthreads();  // drains vmcnt(0): buf[cur] ready; buf[cur^1] free
    // fragment reads first — vmcnt already 0, no forced wait
    f16x8 a1[4], a2[4], b1[4], b2[4];
#pragma unroll
    for (int tm = 0; tm < 4; ++tm) {
      int off = (wm * 64 + tm * 16 + fr) * 32 + fchunk * 8;
      a1[tm] = *(const f16x8*)&Al[cur][0][off];
      a2[tm] = *(const f16x8*)&Al[cur][1][off];
    }
#pragma unroll
    for (int tn = 0; tn < 4; ++tn) {
      int off = (wn * 64 + tn * 16 + fr) * 32 + fchunk * 8;
      b1[tn] = *(const f16x8*)&Bl[cur][0][off];
      b2[tn] = *(const f16x8*)&Bl[cur][1][off];
    }
    // async prefetch of next k-chunk overlaps the MFMA block below
    if (kb < 24) stage(kb + 1, cur ^ 1);
#pragma unroll
    for (int tm = 0; tm < 4; ++tm)
#pragma unroll
      for (int tn = 0; tn < 4; ++tn) {
        acc[tm][tn] = __builtin_amdgcn_mfma_f32_16x16x32_f16(a1[tm], b1[tn], acc[tm][tn], 0, 0, 0);
        acc[tm][tn] = __builtin_amdgcn_mfma_f32_16x16x32_f16(a1[tm], b2[tn], acc[tm][tn], 0, 0, 0);
        acc[tm][tn] = __builtin_amdgcn_mfma_f32_16x16x32_f16(a2[tm], b1[tn], acc[tm][tn], 0, 0, 0);
      }
  }
  __syncthreads();  // all frag reads done; LDS reusable for epilogue

  // epilogue: bias + fast tanh, per-wave LDS transpose, float4 stores
  float* ep = (float*)((wid < 2) ? (void*)&Al[0][0][0] : (void*)&Bl[0][0][0]);
  ep += (wid & 1) * 4096;  // 16 KB region per wave

  float bv[4];
#pragma unroll
  for (int tn = 0; tn < 4; ++tn) {
    int nn = n0 + wn * 64 + tn * 16 + fr;
    bv[tn] = (nn < SIG) ? bias[nn] : 0.0f;
  }
#pragma unroll
  for (int h = 0; h < 2; ++h) {
#pragma unroll
    for (int tm2 = 0; tm2 < 2; ++tm2) {
      int tm = h * 2 + tm2;
#pragma unroll
      for (int tn = 0; tn < 4; ++tn) {
#pragma unroll
        for (int r = 0; r < 4; ++r) {
          int lr = tm2 * 16 + fq * 4 + r;  // 0..31
          int lc = tn * 16 + fr;           // 0..63
          ep[lr * 66 + lc] = fast_tanh(acc[tm][tn][r] + bv[tn]);
        }
      }
    }
    // wave-synchronous readout: 32 rows x 64 cols, float4 per 4 cols
#pragma unroll
    for (int p = 0; p < 2; ++p) {
      int lr = lane & 31;
      int ck = (lane >> 5) * 2 + p;  // 0..3 (16-col chunk)
      int gm = m0 + wm * 64 + h * 32 + lr;
      int gc0 = n0 + wn * 64 + ck * 16;
#pragma unroll
      for (int q = 0; q < 4; ++q) {
        int col = gc0 + q * 4;
        if (col + 3 < SIG) {
          *(float4*)(out + (size_t)gm * SIG + col) =
              *(const float4*)&ep[lr * 66 + ck * 16 + q * 4];
        } else if (col < SIG) {
#pragma unroll
          for (int e = 0; e < 4; ++e) {
            int c2 = col + e;
            if (c2 < SIG) out[(size_t)gm * SIG + c2] = ep[lr * 66 + ck * 16 + q * 4 + e];
          }
        }
      }
    }
  }
}

// ================= FALLBACK PATH (round-1, fp32) =============================
__global__ __launch_bounds__(320) void sig_kernel_fb(
    const float* __restrict__ b_in, float* __restrict__ c_out) {
  int n = blockIdx.x;
  int tid = threadIdx.x;
  __shared__ float S[SIG];
  __shared__ float bc[64 * CH];
  __shared__ float dsh[CH];
  __shared__ float pb[CH];
  for (int i = tid; i < SIG; i += 320) S[i] = 0.0f;
  if (tid < CH) pb[tid] = 0.0f;
  const float* bn = b_in + (size_t)n * T_LEN * CH;
  float* cn = c_out + (size_t)n * T_LEN * SIG;
  const int x0 = tid, x1 = tid + 320;
  const bool has1 = (tid < 305);
  const int a0i = x0 / 125, b0i = (x0 / 25) % 5, c0i = (x0 / 5) % 5, d0i = x0 % 5;
  const int a1i = x1 / 125, b1i = (x1 / 25) % 5, c1i = (x1 / 5) % 5, d1i = x1 % 5;
  const int s2_0 = x0 / 25, s3_0 = x0 / 5, s2_1 = x1 / 25, s3_1 = x1 / 5;
  const bool hasL3 = (tid < 125);
  const int ya = tid / 25, yb = (tid / 5) % 5, yc = tid % 5;
  const bool hasL2 = (tid < 25);
  const int za = tid / 5, zb = tid % 5;
  const bool hasL1 = (tid < CH);
  for (int t = 0; t < T_LEN; ++t) {
    if ((t & 63) == 0) {
      __syncthreads();
      bc[tid] = bn[t * CH + tid];
      __syncthreads();
    }
    if (tid < CH) {
      float cur = bc[(t & 63) * CH + tid];
      dsh[tid] = cur - pb[tid];
      pb[tid] = cur;
    }
    __syncthreads();
    float n4_0, n4_1 = 0.0f, n3 = 0.0f, n2 = 0.0f, n1 = 0.0f;
    {
      float tH = fmaf(0.25f, dsh[a0i], S[a0i]);
      tH = fmaf((1.0f / 3.0f) * dsh[b0i], tH, S[5 + s2_0]);
      tH = fmaf(0.5f * dsh[c0i], tH, S[30 + s3_0]);
      n4_0 = fmaf(dsh[d0i], tH, S[155 + x0]);
    }
    if (has1) {
      float tH = fmaf(0.25f, dsh[a1i], S[a1i]);
      tH = fmaf((1.0f / 3.0f) * dsh[b1i], tH, S[5 + s2_1]);
      tH = fmaf(0.5f * dsh[c1i], tH, S[30 + s3_1]);
      n4_1 = fmaf(dsh[d1i], tH, S[155 + x1]);
    }
    if (hasL3) {
      float tH = fmaf((1.0f / 3.0f), dsh[ya], S[ya]);
      tH = fmaf(0.5f * dsh[yb], tH, S[5 + ya * 5 + yb]);
      n3 = fmaf(dsh[yc], tH, S[30 + tid]);
    }
    if (hasL2) {
      float tH = fmaf(0.5f, dsh[za], S[za]);
      n2 = fmaf(dsh[zb], tH, S[5 + tid]);
    }
    if (hasL1) n1 = S[tid] + dsh[tid];
    __syncthreads();
    S[155 + x0] = n4_0;
    if (has1) S[155 + x1] = n4_1;
    if (hasL3) S[30 + tid] = n3;
    if (hasL2) S[5 + tid] = n2;
    if (hasL1) S[tid] = n1;
    float* crow = cn + (size_t)t * SIG;
    float z = (t == 0) ? 0.0f : 1.0f;
    crow[155 + x0] = n4_0 * z;
    if (has1) crow[155 + x1] = n4_1 * z;
    if (hasL3) crow[30 + tid] = n3 * z;
    if (hasL2) crow[5 + tid] = n2 * z;
    if (hasL1) crow[tid] = n1 * z;
    __syncthreads();
  }
}

#define BM 256
#define BN 64
#define BK 16
__global__ __launch_bounds__(256) void gemm_tanh_fb(
    const float* __restrict__ Cmat, const float* __restrict__ W,
    const float* __restrict__ bias, float* __restrict__ out) {
  __shared__ float As[BK][BM + 4];
  __shared__ float Ws[BK][BN + 4];
  int tid = threadIdx.x;
  int tx = tid & 7, ty = tid >> 3;
  int m0 = blockIdx.x * BM, n0 = blockIdx.y * BN;
  float acc[8][8];
#pragma unroll
  for (int i = 0; i < 8; ++i)
#pragma unroll
    for (int j = 0; j < 8; ++j) acc[i][j] = 0.0f;
  for (int kb = 0; kb < SIG; kb += BK) {
    __syncthreads();
#pragma unroll
    for (int p = 0; p < 4; ++p) {
      int id = tid + p * 256;
      int row = id >> 2, kg = (id & 3) * 4, gk = kb + kg;
      float4 v = make_float4(0.f, 0.f, 0.f, 0.f);
      if (gk < SIG) v = *(const float4*)(Cmat + (size_t)(m0 + row) * SIG + gk);
      As[kg + 0][row] = v.x; As[kg + 1][row] = v.y;
      As[kg + 2][row] = v.z; As[kg + 3][row] = v.w;
    }
    {
      int row = tid >> 2, kg = (tid & 3) * 4, gk = kb + kg, wr = n0 + row;
      float4 v = make_float4(0.f, 0.f, 0.f, 0.f);
      if (gk < SIG && wr < SIG) v = *(const float4*)(W + (size_t)wr * SIG + gk);
      Ws[kg + 0][row] = v.x; Ws[kg + 1][row] = v.y;
      Ws[kg + 2][row] = v.z; Ws[kg + 3][row] = v.w;
    }
    __syncthreads();
#pragma unroll
    for (int k = 0; k < BK; ++k) {
      float af[8], wf[8];
      *(float4*)&af[0] = *(const float4*)&As[k][ty * 8];
      *(float4*)&af[4] = *(const float4*)&As[k][ty * 8 + 4];
      *(float4*)&wf[0] = *(const float4*)&Ws[k][tx * 8];
      *(float4*)&wf[4] = *(const float4*)&Ws[k][tx * 8 + 4];
#pragma unroll
      for (int i = 0; i < 8; ++i)
#pragma unroll
        for (int j = 0; j < 8; ++j) acc[i][j] = fmaf(af[i], wf[j], acc[i][j]);
    }
  }
#pragma unroll
  for (int i = 0; i < 8; ++i) {
    int m = m0 + ty * 8 + i;
    float* orow = out + (size_t)m * SIG;
#pragma unroll
    for (int jj = 0; jj < 8; jj += 4) {
      int col = n0 + tx * 8 + jj;
      if (col < SIG) {
        float4 r;
        r.x = tanhf(acc[i][jj + 0] + bias[col + 0]);
        r.y = tanhf(acc[i][jj + 1] + bias[col + 1]);
        r.z = tanhf(acc[i][jj + 2] + bias[col + 2]);
        r.w = tanhf(acc[i][jj + 3] + bias[col + 3]);
        *(float4*)(orow + col) = r;
      }
    }
  }
}

// ---------------- launch ----------------
extern "C" void kernel_launch(void* const* d_in, const int* in_sizes, int n_in,
                              void* d_out, int out_size, void* d_ws, size_t ws_size,
                              hipStream_t stream) {
  const float* batch = (const float*)d_in[0];
  const float* conv_w = (const float*)d_in[1];
  const float* conv_b = (const float*)d_in[2];
  const float* lin_w = (const float*)d_in[3];
  const float* lin_b = (const float*)d_in[4];
  float* out = (float*)d_out;

  const size_t plane_elems = (size_t)N_B * T_LEN * KP;        // 52,428,800
  const size_t wplane_elems = (size_t)896 * KP;               // 716,800
  const size_t P_elems = (size_t)N_B * N_SEG * SIG;           // 3,194,880
  const size_t bp_elems = (size_t)N_B * T_LEN * CH;           // 327,680
  const size_t need_big = 2 * plane_elems * sizeof(_Float16) +
                          2 * wplane_elems * sizeof(_Float16) +
                          P_elems * sizeof(float);

  if (ws_size >= need_big) {
    _Float16* c1 = (_Float16*)d_ws;
    _Float16* c2 = c1 + plane_elems;
    _Float16* w1 = c2 + plane_elems;
    _Float16* w2 = w1 + wplane_elems;
    float* P = (float*)(w2 + wplane_elems);

    wconv_kernel<<<dim3((896 * KP + 255) / 256), dim3(256), 0, stream>>>(
        lin_w, w1, w2);
    seg_kernel<<<dim3(N_SEG, N_B), dim3(320), 0, stream>>>(batch, conv_w, conv_b, P);
    prefix_kernel<<<dim3(N_B), dim3(640), 0, stream>>>(P);
    emit_kernel<<<dim3(N_SEG, N_B), dim3(320), 0, stream>>>(
        batch, conv_w, conv_b, P, c1, c2);
    gemm_mfma<<<dim3(7, 512), dim3(256), 0, stream>>>(c1, c2, w1, w2, lin_b, out);
  } else {
    float* b_path = (float*)d_ws;
    float* c_sig = (float*)d_ws + bp_elems;
    conv_kernel<<<dim3((N_B * T_LEN + 255) / 256), dim3(256), 0, stream>>>(
        batch, conv_w, conv_b, b_path);
    sig_kernel_fb<<<dim3(N_B), dim3(320), 0, stream>>>(b_path, c_sig);
    gemm_tanh_fb<<<dim3((N_B * T_LEN) / BM, (SIG + BN - 1) / BN), dim3(256), 0, stream>>>(
        c_sig, lin_w, lin_b, out);
  }
}